// Round 2
// 386.277 us; speedup vs baseline: 1.0057x; 1.0057x over previous
//
#include <hip/hip_runtime.h>

// PatchGram, register-direct version (no big LDS tile, no vmcnt(0) convoy):
//  A) thread t owns 4 consecutive channels = float4s g[9t .. 9t+9).
//     9 global float4 loads straight into registers; the 9 spatial phases
//     accumulate thread-locally (phase of (j,comp) = (4j+comp) mod 9).
//     Compiler interleaves partial vmcnt waits with the adds -> no convoy.
//  A2) pooled row = K consecutive channels: butterfly over 1 (CH=512) or
//     2 (CH=1024) shfl_xor steps; one lane per row writes fr[64][9]
//     (rows padded to 12 floats).
//  B) B[dg] = sum_{dd<4} fr[4dg+dd]   (output pooling is linear)
//  C) out[c*16+d] = 1/(36 k^2) * <fr[c], B[d]>, coalesced float4 stores.
//
// LDS = 3.8 KB/block (was 22/40 KB) -> 8 blocks/CU resident, 8-way sample
// interleave per CU keeps the memory pipe busy through the tiny compute tail.

#define N_SAMPLES 6272

template <int CH>
__global__ __launch_bounds__(CH / 4) void patchgram_reg(
    const float* __restrict__ src, float* __restrict__ out)
{
    constexpr int T   = CH / 4;        // threads per block: 128 / 256
    constexpr int K   = CH / 64;       // channels per pooled row: 8 / 16
    constexpr int TPR = K / 4;         // threads per row: 2 / 4
    constexpr float SCALE = 1.0f / (36.0f * (float)(K * K));

    __shared__ float4 fr4[64 * 3];     // fr rows padded to 12 floats
    __shared__ float4 B4[16 * 3];

    const int n = blockIdx.x;
    const int t = threadIdx.x;

    // ---- A: direct-to-register loads + thread-local phase accumulation ----
    const float4* __restrict__ g =
        (const float4*)(src + (size_t)n * (CH * 9)) + t * 9;

    float acc[9];
#pragma unroll
    for (int p = 0; p < 9; ++p) acc[p] = 0.f;
#pragma unroll
    for (int j = 0; j < 9; ++j) {
        const float4 v = g[j];
        acc[(4 * j + 0) % 9] += v.x;
        acc[(4 * j + 1) % 9] += v.y;
        acc[(4 * j + 2) % 9] += v.z;
        acc[(4 * j + 3) % 9] += v.w;
    }

    // ---- A2: combine TPR threads -> one pooled row ----
#pragma unroll
    for (int p = 0; p < 9; ++p) acc[p] += __shfl_xor(acc[p], 1);
    if (TPR == 4) {
#pragma unroll
        for (int p = 0; p < 9; ++p) acc[p] += __shfl_xor(acc[p], 2);
    }
    if ((t & (TPR - 1)) == 0) {
        const int row = t / TPR;       // 0..63
        fr4[row * 3 + 0] = make_float4(acc[0], acc[1], acc[2], acc[3]);
        fr4[row * 3 + 1] = make_float4(acc[4], acc[5], acc[6], acc[7]);
        fr4[row * 3 + 2] = make_float4(acc[8], 0.f, 0.f, 0.f);
    }
    __syncthreads();

    // ---- B: pooled rows ----
    for (int i = t; i < 144; i += T) {
        const int dg = i / 9;
        const int p  = i - dg * 9;
        const float* fr = (const float*)fr4;
        ((float*)B4)[dg * 12 + p] =
            fr[(4 * dg + 0) * 12 + p] + fr[(4 * dg + 1) * 12 + p] +
            fr[(4 * dg + 2) * 12 + p] + fr[(4 * dg + 3) * 12 + p];
    }
    __syncthreads();

    // ---- C: out[c][d] = SCALE * <fr[c], B[d]> ----
    constexpr int OPT = 1024 / T;      // outputs per thread: 4 / 8
    constexpr int GPR = 16 / OPT;      // d-groups per row: 4 / 2
    const int c     = t / GPR;         // 0..63
    const int dbase = (t % GPR) * OPT;

    const float4 a0 = fr4[c * 3 + 0];
    const float4 a1 = fr4[c * 3 + 1];
    const float4 a2 = fr4[c * 3 + 2];

    float o[OPT];
#pragma unroll
    for (int j = 0; j < OPT; ++j) {
        const int d = dbase + j;
        const float4 b0 = B4[d * 3 + 0];
        const float4 b1 = B4[d * 3 + 1];
        const float4 b2 = B4[d * 3 + 2];
        o[j] = (a0.x * b0.x + a0.y * b0.y + a0.z * b0.z + a0.w * b0.w
              + a1.x * b1.x + a1.y * b1.y + a1.z * b1.z + a1.w * b1.w
              + a2.x * b2.x) * SCALE;
    }

    float* obase = out + (size_t)n * 2048 + c * 16 + dbase;
#pragma unroll
    for (int q = 0; q < OPT / 4; ++q) {
        ((float4*)obase)[q] =
            make_float4(o[4 * q + 0], o[4 * q + 1], o[4 * q + 2], o[4 * q + 3]);
    }
}

extern "C" void kernel_launch(void* const* d_in, const int* in_sizes, int n_in,
                              void* d_out, int out_size, void* d_ws, size_t ws_size,
                              hipStream_t stream) {
    const float* f0 = (const float*)d_in[0];   // [6272, 512, 3, 3]
    const float* f1 = (const float*)d_in[1];   // [6272, 1024, 3, 3]
    float* out = (float*)d_out;                // [6272, 2, 1024]
    patchgram_reg<512><<<N_SAMPLES, 128, 0, stream>>>(f0, out);
    patchgram_reg<1024><<<N_SAMPLES, 256, 0, stream>>>(f1, out + 1024);
}